// Round 10
// baseline (547.970 us; speedup 1.0000x reference)
//
#include <hip/hip_runtime.h>
#include <float.h>
#include <math.h>

#define NUM_USERS 100000
#define NUM_ITEMS 50000
#define NNODES    150000
#define DIM       64
#define NEDGE     2000000
#define BATCH     1024
#define SEL_CAP   (1 << 18)
#define LOGIT_BLOCKS 512

#define HBLK     256                    // edge slices
#define EPB      7816                   // ceil(NEDGE/HBLK) rounded to x4
#define NBUK     293                    // buckets of 512 nodes (293*512=150016)

__device__ __forceinline__ float wave_sum64(float v) {
    #pragma unroll
    for (int off = 32; off > 0; off >>= 1) v += __shfl_xor(v, off, 64);
    return v;
}

__device__ __forceinline__ float bf2f(unsigned short s) {
    return __uint_as_float(((unsigned int)s) << 16);
}
__device__ __forceinline__ unsigned short f2bf(float f) {   // RNE
    unsigned int u = __float_as_uint(f);
    return (unsigned short)((u + 0x7fffu + ((u >> 16) & 1u)) >> 16);
}

// ---- stage 1: per-slice 293-bucket histograms (row & col), counts only ---

__global__ __launch_bounds__(1024) void bhist_kernel(
        const int* __restrict__ row, const int* __restrict__ col,
        unsigned short* __restrict__ cntR, unsigned short* __restrict__ cntC) {
    __shared__ unsigned int hr[NBUK], hc[NBUK];
    int blk = blockIdx.x;
    int e0 = blk * EPB;
    int e1 = e0 + EPB; if (e1 > NEDGE) e1 = NEDGE;
    for (int i = threadIdx.x; i < NBUK; i += 1024) { hr[i] = 0; hc[i] = 0; }
    __syncthreads();
    for (int base = e0 + (int)threadIdx.x * 4; base < e1; base += 4096) {
        if (base + 4 <= e1) {
            int4 r4 = *(const int4*)(row + base);
            int4 c4 = *(const int4*)(col + base);
            atomicAdd(&hr[r4.x >> 9], 1u); atomicAdd(&hr[r4.y >> 9], 1u);
            atomicAdd(&hr[r4.z >> 9], 1u); atomicAdd(&hr[r4.w >> 9], 1u);
            atomicAdd(&hc[c4.x >> 9], 1u); atomicAdd(&hc[c4.y >> 9], 1u);
            atomicAdd(&hc[c4.z >> 9], 1u); atomicAdd(&hc[c4.w >> 9], 1u);
        } else {
            for (int e = base; e < e1; ++e) {
                atomicAdd(&hr[row[e] >> 9], 1u);
                atomicAdd(&hc[col[e] >> 9], 1u);
            }
        }
    }
    __syncthreads();
    for (int i = threadIdx.x; i < NBUK; i += 1024) {
        cntR[(size_t)blk * NBUK + i] = (unsigned short)hr[i];
        cntC[(size_t)blk * NBUK + i] = (unsigned short)hc[i];
    }
}

// ---- stage 2: per-bucket prefix over slices (in-place u16) + bucket bases

__global__ __launch_bounds__(512) void bprefix_kernel(
        unsigned short* __restrict__ cntR, unsigned short* __restrict__ cntC,
        int* __restrict__ baseR, int* __restrict__ baseC) {
    unsigned short* cnt = blockIdx.x ? cntC : cntR;
    int* base = blockIdx.x ? baseC : baseR;
    __shared__ int tot[512], sm[512];
    int t = threadIdx.x;
    int run = 0;
    if (t < NBUK) {
        for (int s = 0; s < HBLK; ++s) {
            int v = cnt[(size_t)s * NBUK + t];
            cnt[(size_t)s * NBUK + t] = (unsigned short)run;
            run += v;
        }
    }
    tot[t] = (t < NBUK) ? run : 0;
    sm[t] = tot[t];
    __syncthreads();
    for (int off = 1; off < 512; off <<= 1) {
        int v = (t >= off) ? sm[t - off] : 0;
        __syncthreads();
        sm[t] += v;
        __syncthreads();
    }
    if (t < NBUK) base[t] = sm[t] - tot[t];
    if (t == NBUK - 1) base[NBUK] = sm[t];     // == NEDGE
}

// ---- stage 3: LDS-staged slice sort -> coalesced burst write-out --------
// Per-entry line migration was the R8 bottleneck (WRITE 105 MB for 12 MB of
// payload): runs were written 4B-at-a-time, interleaved with other XCDs.
// v2: sort the slice into LDS, then each wave copies whole runs to global
// as consecutive-lane bursts -> ~1 migration per line.

__global__ __launch_bounds__(1024) void bscatter_kernel(
        const int* __restrict__ row, const int* __restrict__ col,
        const unsigned short* __restrict__ cntR, const unsigned short* __restrict__ cntC,
        const int* __restrict__ baseR, const int* __restrict__ baseC,
        const int* __restrict__ ucnt,
        unsigned short* __restrict__ midR, unsigned int* __restrict__ midC,
        int* __restrict__ n_sel, int* __restrict__ sel_col, float* __restrict__ sel_w) {
    __shared__ unsigned int hc[NBUK], hr[NBUK];
    __shared__ int lofC[NBUK], lofR[NBUK];
    __shared__ int posC[NBUK], posR[NBUK];
    __shared__ int scan_tmp[512];
    __shared__ unsigned int   stC[EPB];
    __shared__ unsigned short stR[EPB];
    int blk = blockIdx.x;
    int t = threadIdx.x;
    for (int i = t; i < NBUK; i += 1024) {
        hc[i] = 0; hr[i] = 0;
        posC[i] = baseC[i] + (int)cntC[(size_t)blk * NBUK + i];
        posR[i] = baseR[i] + (int)cntR[(size_t)blk * NBUK + i];
    }
    __syncthreads();
    int e0 = blk * EPB;
    int e1 = e0 + EPB; if (e1 > NEDGE) e1 = NEDGE;
    // phase A: local ranks via returning LDS atomics (kept in registers)
    unsigned char kcA[8], krA[8];
    int it = 0;
    for (int base = e0 + t * 4; base < e1; base += 4096, ++it) {
        if (base + 4 <= e1) {
            int4 r4 = *(const int4*)(row + base);
            int4 c4 = *(const int4*)(col + base);
            kcA[it*4+0] = (unsigned char)atomicAdd(&hc[c4.x >> 9], 1u);
            kcA[it*4+1] = (unsigned char)atomicAdd(&hc[c4.y >> 9], 1u);
            kcA[it*4+2] = (unsigned char)atomicAdd(&hc[c4.z >> 9], 1u);
            kcA[it*4+3] = (unsigned char)atomicAdd(&hc[c4.w >> 9], 1u);
            krA[it*4+0] = (unsigned char)atomicAdd(&hr[r4.x >> 9], 1u);
            krA[it*4+1] = (unsigned char)atomicAdd(&hr[r4.y >> 9], 1u);
            krA[it*4+2] = (unsigned char)atomicAdd(&hr[r4.z >> 9], 1u);
            krA[it*4+3] = (unsigned char)atomicAdd(&hr[r4.w >> 9], 1u);
        } else {
            for (int e = base; e < e1; ++e) {
                kcA[it*4 + (e - base)] = (unsigned char)atomicAdd(&hc[col[e] >> 9], 1u);
                krA[it*4 + (e - base)] = (unsigned char)atomicAdd(&hr[row[e] >> 9], 1u);
            }
        }
    }
    __syncthreads();
    // local exclusive scans (293 entries) for col and row
    if (t < 512) scan_tmp[t] = (t < NBUK) ? (int)hc[t] : 0;
    __syncthreads();
    for (int off = 1; off < 512; off <<= 1) {
        int v = 0;
        if (t < 512 && t >= off) v = scan_tmp[t - off];
        __syncthreads();
        if (t < 512) scan_tmp[t] += v;
        __syncthreads();
    }
    if (t < NBUK) lofC[t] = scan_tmp[t] - (int)hc[t];
    __syncthreads();
    if (t < 512) scan_tmp[t] = (t < NBUK) ? (int)hr[t] : 0;
    __syncthreads();
    for (int off = 1; off < 512; off <<= 1) {
        int v = 0;
        if (t < 512 && t >= off) v = scan_tmp[t - off];
        __syncthreads();
        if (t < 512) scan_tmp[t] += v;
        __syncthreads();
    }
    if (t < NBUK) lofR[t] = scan_tmp[t] - (int)hr[t];
    __syncthreads();
    // phase B: reload edges (L2-warm), scatter into LDS staging + selection
    it = 0;
    for (int base = e0 + t * 4; base < e1; base += 4096, ++it) {
        int nv = (base + 4 <= e1) ? 4 : (e1 - base);
        int r[4], c[4];
        if (nv == 4) {
            int4 r4 = *(const int4*)(row + base);
            int4 c4 = *(const int4*)(col + base);
            r[0] = r4.x; r[1] = r4.y; r[2] = r4.z; r[3] = r4.w;
            c[0] = c4.x; c[1] = c4.y; c[2] = c4.z; c[3] = c4.w;
        } else {
            for (int j = 0; j < nv; ++j) { r[j] = row[base + j]; c[j] = col[base + j]; }
        }
        #pragma unroll
        for (int j = 0; j < 4; ++j) {
            if (j < nv) {
                stC[lofC[c[j] >> 9] + (int)kcA[it*4+j]] =
                    ((unsigned int)(c[j] & 511) << 18) | (unsigned int)r[j];
                stR[lofR[r[j] >> 9] + (int)krA[it*4+j]] = (unsigned short)(r[j] & 511);
                int cu = ucnt[r[j]];
                if (cu > 0) {
                    int i = atomicAdd(n_sel, 1);
                    if (i < SEL_CAP) { sel_col[i] = c[j]; sel_w[i] = (float)cu; }
                }
            }
        }
    }
    __syncthreads();
    // write-out: wave w copies buckets w, w+16, ... as coalesced bursts
    int wave = t >> 6, lane = t & 63;
    for (int b = wave; b < NBUK; b += 16) {
        int n = (int)hc[b], lo = lofC[b], dst = posC[b];
        for (int i = lane; i < n; i += 64) midC[dst + i] = stC[lo + i];
        n = (int)hr[b]; lo = lofR[b]; dst = posR[b];
        for (int i = lane; i < n; i += 64) midR[dst + i] = stR[lo + i];
    }
}

// ---- stage 4a: per col-bucket: count -> scan -> rptr + permute to CSR ----

__global__ __launch_bounds__(1024) void bfinal_col_kernel(
        const unsigned int* __restrict__ midC, const int* __restrict__ baseC,
        int* __restrict__ rptr, int* __restrict__ src_sorted) {
    __shared__ int cnt[512], sm[512], cur[512];
    int b = blockIdx.x;
    int s0 = baseC[b], s1 = baseC[b + 1];
    int t = threadIdx.x;
    if (t < 512) cnt[t] = 0;
    __syncthreads();
    for (int i = s0 + t; i < s1; i += 1024) atomicAdd(&cnt[midC[i] >> 18], 1);
    __syncthreads();
    if (t < 512) sm[t] = cnt[t];
    __syncthreads();
    for (int off = 1; off < 512; off <<= 1) {
        int v = 0;
        if (t < 512 && t >= off) v = sm[t - off];
        __syncthreads();
        if (t < 512) sm[t] += v;
        __syncthreads();
    }
    if (t < 512) {
        int excl = s0 + sm[t] - cnt[t];
        int n = b * 512 + t;
        if (n < NNODES) rptr[n] = excl;
        cur[t] = excl;
    }
    if (b == NBUK - 1 && t == 0) rptr[NNODES] = s1;   // == NEDGE
    __syncthreads();
    for (int i = s0 + t; i < s1; i += 1024) {
        unsigned int v = midC[i];
        int dst = atomicAdd(&cur[v >> 18], 1);
        src_sorted[dst] = (int)(v & 0x3FFFFu);
    }
}

// ---- stage 4b: per row-bucket: count -> dinv / dinv2 ---------------------

__global__ __launch_bounds__(1024) void bfinal_row_kernel(
        const unsigned short* __restrict__ midR, const int* __restrict__ baseR,
        float* __restrict__ dinv, float* __restrict__ dinv2) {
    __shared__ int cnt[512];
    int b = blockIdx.x;
    int s0 = baseR[b], s1 = baseR[b + 1];
    int t = threadIdx.x;
    if (t < 512) cnt[t] = 0;
    __syncthreads();
    for (int i = s0 + t; i < s1; i += 1024) atomicAdd(&cnt[midR[i]], 1);
    __syncthreads();
    if (t < 512) {
        int n = b * 512 + t;
        if (n < NNODES) {
            float d = fmaxf((float)cnt[t], 1.0f);
            dinv[n] = rsqrtf(d);
            dinv2[n] = 1.0f / d;
        }
    }
}

// ---- f32 embed -> bf16 y0 = dinv * x0 -----------------------------------

__global__ void cvt_kernel(const float4* __restrict__ src, uint2* __restrict__ dst,
                           const float* __restrict__ dinv) {
    int t = blockIdx.x * blockDim.x + threadIdx.x;   // one uint2 = 4 bf16
    if (t >= NNODES * 16) return;
    float d = dinv[t >> 4];
    float4 v = src[t];
    unsigned int w0 = (unsigned int)f2bf(v.x * d) | ((unsigned int)f2bf(v.y * d) << 16);
    unsigned int w1 = (unsigned int)f2bf(v.z * d) | ((unsigned int)f2bf(v.w * d) << 16);
    dst[t] = make_uint2(w0, w1);
}

// ---- propagation in y-space: out[c] = scale[c] * sum over in-edges y[r] --

__global__ void prop_kernel(const uint2* __restrict__ x_in, uint2* __restrict__ x_out,
                            const int* __restrict__ ptr, const int* __restrict__ src,
                            const float* __restrict__ scale) {
    int gid  = blockIdx.x * blockDim.x + threadIdx.x;
    int node = gid >> 4;       // 16 lanes per node
    int sl   = gid & 15;       // lane's 4-dim slot within the row
    if (node >= NNODES) return;
    int s = ptr[node], e = ptr[node + 1];
    float a0 = 0.f, a1 = 0.f, a2 = 0.f, a3 = 0.f;
    int i = s;
    for (; i + 4 <= e; i += 4) {
        int s0 = src[i], s1 = src[i + 1], s2 = src[i + 2], s3 = src[i + 3];
        uint2 w0 = x_in[s0 * 16 + sl];
        uint2 w1 = x_in[s1 * 16 + sl];
        uint2 w2 = x_in[s2 * 16 + sl];
        uint2 w3 = x_in[s3 * 16 + sl];
        a0 += __uint_as_float(w0.x << 16); a1 += __uint_as_float(w0.x & 0xffff0000u);
        a2 += __uint_as_float(w0.y << 16); a3 += __uint_as_float(w0.y & 0xffff0000u);
        a0 += __uint_as_float(w1.x << 16); a1 += __uint_as_float(w1.x & 0xffff0000u);
        a2 += __uint_as_float(w1.y << 16); a3 += __uint_as_float(w1.y & 0xffff0000u);
        a0 += __uint_as_float(w2.x << 16); a1 += __uint_as_float(w2.x & 0xffff0000u);
        a2 += __uint_as_float(w2.y << 16); a3 += __uint_as_float(w2.y & 0xffff0000u);
        a0 += __uint_as_float(w3.x << 16); a1 += __uint_as_float(w3.x & 0xffff0000u);
        a2 += __uint_as_float(w3.y << 16); a3 += __uint_as_float(w3.y & 0xffff0000u);
    }
    for (; i < e; ++i) {
        uint2 w0 = x_in[src[i] * 16 + sl];
        a0 += __uint_as_float(w0.x << 16); a1 += __uint_as_float(w0.x & 0xffff0000u);
        a2 += __uint_as_float(w0.y << 16); a3 += __uint_as_float(w0.y & 0xffff0000u);
    }
    float sc = scale[node];
    unsigned int o0 = (unsigned int)f2bf(a0 * sc) | ((unsigned int)f2bf(a1 * sc) << 16);
    unsigned int o1 = (unsigned int)f2bf(a2 * sc) | ((unsigned int)f2bf(a3 * sc) << 16);
    x_out[node * 16 + sl] = make_uint2(o0, o1);
}

// ---- batch / softmax part (x is bf16) -----------------------------------

__global__ void ucnt_kernel(const int* __restrict__ users, int* __restrict__ ucnt) {
    int b = blockIdx.x * blockDim.x + threadIdx.x;
    if (b < BATCH) atomicAdd(&ucnt[users[b]], 1);
}

__global__ void ctx_kernel(const unsigned short* __restrict__ x, const int* __restrict__ users,
                           float* __restrict__ ctx) {
    __shared__ float sm[256];
    int lane = threadIdx.x & 63, wl = threadIdx.x >> 6;
    float acc = 0.0f;
    for (int b = wl; b < BATCH; b += 4) acc += bf2f(x[users[b] * DIM + lane]);
    sm[threadIdx.x] = acc; __syncthreads();
    if (wl == 0)
        ctx[lane] = (sm[lane] + sm[64 + lane] + sm[128 + lane] + sm[192 + lane]) * (1.0f / BATCH);
}

__global__ void logit_kernel(const unsigned short* __restrict__ x, const float* __restrict__ ctx,
                             const int* __restrict__ sel_col, const int* __restrict__ n_sel_p,
                             float* __restrict__ sel_logit, float* __restrict__ blk_max) {
    __shared__ float sm[4];
    int lane = threadIdx.x & 63, wl = threadIdx.x >> 6;
    int n = *n_sel_p; if (n > SEL_CAP) n = SEL_CAP;
    float c = ctx[lane];
    float bmax = -FLT_MAX;
    int stride = gridDim.x * 4;
    for (int idx = blockIdx.x * 4 + wl; idx < n; idx += stride) {
        int node = sel_col[idx];
        float v = bf2f(x[node * DIM + lane]) * c;
        v = wave_sum64(v);
        if (lane == 0) sel_logit[idx] = v;
        bmax = fmaxf(bmax, v);
    }
    if (lane == 0) sm[wl] = bmax;
    __syncthreads();
    if (threadIdx.x == 0)
        blk_max[blockIdx.x] = fmaxf(fmaxf(sm[0], sm[1]), fmaxf(sm[2], sm[3]));
}

__global__ void max_kernel(const float* __restrict__ blk_max, float* __restrict__ mx) {
    __shared__ float sm[256];
    int t = threadIdx.x;
    float m = fmaxf(blk_max[t], blk_max[t + 256]);
    sm[t] = m; __syncthreads();
    for (int off = 128; off > 0; off >>= 1) {
        if (t < off) sm[t] = fmaxf(sm[t], sm[t + off]);
        __syncthreads();
    }
    if (t == 0) *mx = sm[0];
}

__global__ void accum_kernel(const unsigned short* __restrict__ x, const int* __restrict__ sel_col,
                             const float* __restrict__ sel_w, const float* __restrict__ sel_logit,
                             const int* __restrict__ n_sel_p, const float* __restrict__ mx_p,
                             float* __restrict__ S, float* __restrict__ zp) {
    __shared__ float smS[4 * 64];
    __shared__ float smZ[4];
    int lane = threadIdx.x & 63, wl = threadIdx.x >> 6;
    int n = *n_sel_p; if (n > SEL_CAP) n = SEL_CAP;
    float mx = *mx_p;
    float accS = 0.0f, accZ = 0.0f;
    int stride = gridDim.x * 4;
    for (int idx = blockIdx.x * 4 + wl; idx < n; idx += stride) {
        int node = sel_col[idx];
        float w = sel_w[idx] * __expf(sel_logit[idx] - mx);
        accS = fmaf(w, bf2f(x[node * DIM + lane]), accS);
        accZ += w;
    }
    smS[wl * 64 + lane] = accS;
    if (lane == 0) smZ[wl] = accZ;
    __syncthreads();
    if (wl == 0) {
        float s = smS[lane] + smS[64 + lane] + smS[128 + lane] + smS[192 + lane];
        atomicAdd(&S[lane], s);
    }
    if (threadIdx.x == 0) atomicAdd(zp, smZ[0] + smZ[1] + smZ[2] + smZ[3]);
}

__global__ void score_kernel(const unsigned short* __restrict__ x, const int* __restrict__ users,
                             const int* __restrict__ items, const float* __restrict__ S,
                             const float* __restrict__ zp, float* __restrict__ out) {
    int gid = blockIdx.x * blockDim.x + threadIdx.x;
    int b = gid >> 6, lane = gid & 63;
    if (b >= BATCH) return;
    float z = fmaxf(*zp, 1e-12f);
    float na = S[lane] / z;
    int u = users[b], it = items[b] + NUM_USERS;
    float v = bf2f(x[u * DIM + lane]) * (bf2f(x[it * DIM + lane]) + na);
    v = wave_sum64(v);
    if (lane == 0) out[b] = 1.0f / (1.0f + __expf(-v));
}

// ---- launch -------------------------------------------------------------

extern "C" void kernel_launch(void* const* d_in, const int* in_sizes, int n_in,
                              void* d_out, int out_size, void* d_ws, size_t ws_size,
                              hipStream_t stream) {
    const float* embed = (const float*)d_in[0];
    const int*   edge  = (const int*)d_in[1];
    const int*   row   = edge;
    const int*   col   = edge + NEDGE;
    const int*   users = (const int*)d_in[2];
    const int*   items = (const int*)d_in[3];
    float*       out   = (float*)d_out;
    char*        ws    = (char*)d_ws;

    size_t off = 0;
    auto A = [&](size_t bytes) { size_t o = off; off += (bytes + 255) & ~(size_t)255; return o; };
    // big region: midC (8 MB) + midR (4 MB) during build; xa (19.2 MB) after
    size_t o_big   = A((size_t)NNODES * DIM * 2);      // 19.2 MB
    size_t o_xb    = A((size_t)NNODES * DIM * 2);      // 19.2 MB
    size_t o_src   = A((size_t)NEDGE * 4);             // 8 MB, alive thru prop
    size_t o_cntR  = A((size_t)HBLK * NBUK * 2);       // 150 KB
    size_t o_cntC  = A((size_t)HBLK * NBUK * 2);
    size_t o_baseR = A((size_t)(NBUK + 1) * 4);
    size_t o_baseC = A((size_t)(NBUK + 1) * 4);
    size_t o_selc  = A((size_t)SEL_CAP * 4);
    size_t o_selw  = A((size_t)SEL_CAP * 4);
    size_t o_sell  = A((size_t)SEL_CAP * 4);
    size_t o_zero  = off;                              // ---- zeroed block ----
    size_t o_ucnt  = A((size_t)NNODES * 4);
    size_t o_misc  = A(1024);                          // n_sel@0, mx@4, z@8, S@256
    size_t zero_bytes = off - o_zero;                  // ---- end zero -------
    size_t o_dinv  = A((size_t)NNODES * 4);
    size_t o_dinv2 = A((size_t)NNODES * 4);
    size_t o_rptr  = A((size_t)(NNODES + 1) * 4);
    size_t o_bmax  = A((size_t)LOGIT_BLOCKS * 4);
    size_t o_ctx   = A(256);

    unsigned int*   midC = (unsigned int*)(ws + o_big);                // 8 MB
    unsigned short* midR = (unsigned short*)(ws + o_big + (size_t)NEDGE * 4);  // 4 MB
    unsigned short* xa   = (unsigned short*)(ws + o_big);              // overlay after build
    unsigned short* xb   = (unsigned short*)(ws + o_xb);
    int*   srcS  = (int*)(ws + o_src);
    unsigned short* cntR = (unsigned short*)(ws + o_cntR);
    unsigned short* cntC = (unsigned short*)(ws + o_cntC);
    int*   baseR = (int*)(ws + o_baseR);
    int*   baseC = (int*)(ws + o_baseC);
    int*   selc  = (int*)(ws + o_selc);
    float* selw  = (float*)(ws + o_selw);
    float* sell  = (float*)(ws + o_sell);
    int*   ucnt  = (int*)(ws + o_ucnt);
    int*   nsel  = (int*)(ws + o_misc);
    float* mx    = (float*)(ws + o_misc + 4);
    float* zp    = (float*)(ws + o_misc + 8);
    float* S     = (float*)(ws + o_misc + 256);
    float* dinv  = (float*)(ws + o_dinv);
    float* dinv2 = (float*)(ws + o_dinv2);
    int*   rptr  = (int*)(ws + o_rptr);
    float* bmax  = (float*)(ws + o_bmax);
    float* ctx   = (float*)(ws + o_ctx);

    hipMemsetAsync(ws + o_zero, 0, zero_bytes, stream);

    ucnt_kernel<<<(BATCH + 255) / 256, 256, 0, stream>>>(users, ucnt);

    // atomic-free CSR build: bucket radix, LDS-staged burst write-out
    bhist_kernel<<<HBLK, 1024, 0, stream>>>(row, col, cntR, cntC);
    bprefix_kernel<<<2, 512, 0, stream>>>(cntR, cntC, baseR, baseC);
    bscatter_kernel<<<HBLK, 1024, 0, stream>>>(row, col, cntR, cntC,
                                               baseR, baseC, ucnt, midR, midC,
                                               nsel, selc, selw);
    bfinal_col_kernel<<<NBUK, 1024, 0, stream>>>(midC, baseC, rptr, srcS);
    bfinal_row_kernel<<<NBUK, 1024, 0, stream>>>(midR, baseR, dinv, dinv2);

    // y0 = bf16(dinv*embed); layers: y->y (dinv2), y->y (dinv2), y->x (dinv)
    cvt_kernel<<<(NNODES * 16 + 255) / 256, 256, 0, stream>>>((const float4*)embed, (uint2*)xa, dinv);
    int prop_blocks = (NNODES * 16 + 255) / 256;
    prop_kernel<<<prop_blocks, 256, 0, stream>>>((const uint2*)xa, (uint2*)xb, rptr, srcS, dinv2);
    prop_kernel<<<prop_blocks, 256, 0, stream>>>((const uint2*)xb, (uint2*)xa, rptr, srcS, dinv2);
    prop_kernel<<<prop_blocks, 256, 0, stream>>>((const uint2*)xa, (uint2*)xb, rptr, srcS, dinv);
    // final x lives in xb

    // batch softmax aggregation over selected edges
    ctx_kernel<<<1, 256, 0, stream>>>(xb, users, ctx);
    logit_kernel<<<LOGIT_BLOCKS, 256, 0, stream>>>(xb, ctx, selc, nsel, sell, bmax);
    max_kernel<<<1, 256, 0, stream>>>(bmax, mx);
    accum_kernel<<<LOGIT_BLOCKS, 256, 0, stream>>>(xb, selc, selw, sell, nsel, mx, S, zp);

    // final scores
    score_kernel<<<(BATCH * 64 + 255) / 256, 256, 0, stream>>>(xb, users, items, S, zp, out);
}